// Round 7
// baseline (708.059 us; speedup 1.0000x reference)
//
#include <hip/hip_runtime.h>
#include <math.h>
#include <float.h>

#define VOCAB    32000
#define NT       256
#define NWAVES   (NT / 64)
#define CAP      1024    // LDS candidate buffer (fallback path)
#define CAPG     512     // per-row global candidate buffer; E=228, sigma~15 -> +19 sigma
#define KMAX     64      // >= top_k (50)
#define KREF     24.0f
#define THETA0   14.0f
#define LOG2E    1.4426950408889634f
#define THT      ((THETA0 - KREF) * LOG2E)
#define FBDELTA  (12.0f * LOG2E)
#define NCHUNK   (VOCAB / 4)   // 8000 float4 per row
#define WCPR     125           // wave-chunks (64 float4 = 1KB) per row: 8000/64

typedef float vf4 __attribute__((ext_vector_type(4)));

// TOPOLOGY round: R5 (2048 scattered row-streams) ~0.88 GB/s/stream; R6 (512
// streams, 1/4 concurrency) 2.2 GB/s/stream -> scatter hurts, concurrency helps.
// Only untested config: full concurrency + CONTIGUOUS instantaneous window =
// grid-stride (m13's 6.3 TB/s topology). Kernel A sweeps logits grid-stride,
// emitting per-chunk partial sums/maxes and per-row candidates (exact v/T values)
// to workspace; kernel B (tiny) reduces partials in FIXED order and runs the
// verbatim R5 rank/top-p/Gumbel. Discrete outputs identical: rank is an exact
// total order over (val desc, idx asc); arrival order irrelevant.

// ---------------- Kernel A: grid-stride sweep ----------------
#define SWEEP(vv, wc, row, cir)                                                   \
    {                                                                             \
        float t0 = fmaf((vv).x, a, b);                                            \
        float t1 = fmaf((vv).y, a, b);                                            \
        float t2 = fmaf((vv).z, a, b);                                            \
        float t3 = fmaf((vv).w, a, b);                                            \
        float s  = (exp2f(t0) + exp2f(t2)) + (exp2f(t1) + exp2f(t3));             \
        float mx = fmaxf(fmaxf(t0, t1), fmaxf(t2, t3));                           \
        _Pragma("unroll")                                                         \
        for (int o = 32; o > 0; o >>= 1) {                                        \
            s  += __shfl_down(s, o, 64);                                          \
            mx  = fmaxf(mx, __shfl_down(mx, o, 64));                              \
        }                                                                         \
        if (lane == 0) { psum[wc] = s; pmaxv[wc] = mx; }                          \
        int bi = ((cir) * 64 + lane) * 4;                                         \
        if (t0 > THT) { int p = atomicAdd(&gcnt[row], 1); if (p < CAPG) { gval[(size_t)(row)*CAPG + p] = (vv).x / T; gidx[(size_t)(row)*CAPG + p] = bi;     } } \
        if (t1 > THT) { int p = atomicAdd(&gcnt[row], 1); if (p < CAPG) { gval[(size_t)(row)*CAPG + p] = (vv).y / T; gidx[(size_t)(row)*CAPG + p] = bi + 1; } } \
        if (t2 > THT) { int p = atomicAdd(&gcnt[row], 1); if (p < CAPG) { gval[(size_t)(row)*CAPG + p] = (vv).z / T; gidx[(size_t)(row)*CAPG + p] = bi + 2; } } \
        if (t3 > THT) { int p = atomicAdd(&gcnt[row], 1); if (p < CAPG) { gval[(size_t)(row)*CAPG + p] = (vv).w / T; gidx[(size_t)(row)*CAPG + p] = bi + 3; } } \
    }

__global__ __launch_bounds__(NT, 8) void sweep_kernel(
    const float* __restrict__ logits,
    const float* __restrict__ tempP,
    int*   __restrict__ gcnt,
    float* __restrict__ psum,
    float* __restrict__ pmaxv,
    float* __restrict__ gval,
    int*   __restrict__ gidx,
    int nRows)
{
    const int tid  = threadIdx.x;
    const int lane = tid & 63;
    const int wid  = tid >> 6;
    const float T = tempP[0];
    const float a = (1.0f / T) * LOG2E;
    const float b = -(KREF * LOG2E);
    const int totalWC = nRows * WCPR;
    const int mainWC  = totalWC & ~3;
    const int gw = blockIdx.x * NWAVES + wid;
    const int nw = gridDim.x * NWAVES;

    for (int wcb = gw * 4; wcb < mainWC; wcb += nw * 4) {
        int row0 = (wcb + 0) / WCPR, cir0 = (wcb + 0) - row0 * WCPR;
        int row1 = (wcb + 1) / WCPR, cir1 = (wcb + 1) - row1 * WCPR;
        int row2 = (wcb + 2) / WCPR, cir2 = (wcb + 2) - row2 * WCPR;
        int row3 = (wcb + 3) / WCPR, cir3 = (wcb + 3) - row3 * WCPR;
        const vf4* p0 = (const vf4*)logits + ((size_t)row0 * NCHUNK + cir0 * 64 + lane);
        const vf4* p1 = (const vf4*)logits + ((size_t)row1 * NCHUNK + cir1 * 64 + lane);
        const vf4* p2 = (const vf4*)logits + ((size_t)row2 * NCHUNK + cir2 * 64 + lane);
        const vf4* p3 = (const vf4*)logits + ((size_t)row3 * NCHUNK + cir3 * 64 + lane);
        vf4 r0 = __builtin_nontemporal_load(p0);
        vf4 r1 = __builtin_nontemporal_load(p1);
        vf4 r2 = __builtin_nontemporal_load(p2);
        vf4 r3 = __builtin_nontemporal_load(p3);
        SWEEP(r0, wcb + 0, row0, cir0);
        SWEEP(r1, wcb + 1, row1, cir1);
        SWEEP(r2, wcb + 2, row2, cir2);
        SWEEP(r3, wcb + 3, row3, cir3);
    }
    // tail chunks (totalWC % 4), at most 3 globally
    for (int wc = mainWC + gw; wc < totalWC; wc += nw) {
        int row = wc / WCPR, cir = wc - row * WCPR;
        const vf4* p = (const vf4*)logits + ((size_t)row * NCHUNK + cir * 64 + lane);
        vf4 r = __builtin_nontemporal_load(p);
        SWEEP(r, wc, row, cir);
    }
}

// ---------------- Kernel B: per-row finalize (tiny) ----------------
__global__ __launch_bounds__(NT) void finalize_kernel(
    const float* __restrict__ logits,
    const float* __restrict__ gumbel,
    const float* __restrict__ tempP,
    const float* __restrict__ toppP,
    const int*   __restrict__ topkP,
    const int*   __restrict__ gcnt,
    const float* __restrict__ psum,
    const float* __restrict__ pmaxv,
    const float* __restrict__ gval,
    const int*   __restrict__ gidx,
    float* __restrict__ out_conf,
    float* __restrict__ out_x0,
    float* __restrict__ out_iconf)
{
    const int row = blockIdx.x;
    const int tid = threadIdx.x;
    const int lane = tid & 63;
    const int wid  = tid >> 6;
    const size_t base = (size_t)row * VOCAB;
    const float T = tempP[0];
    const float a = (1.0f / T) * LOG2E;
    const float b = -(KREF * LOG2E);

    __shared__ float s_val[CAP];
    __shared__ int   s_idx[CAP];
    __shared__ int   s_cnt;
    __shared__ float redS[WCPR], redM[WCPR];
    __shared__ float sh_S, sh_m;
    __shared__ float so_val[KMAX];
    __shared__ int   so_idx[KMAX];
    __shared__ int   sh_nk;
    __shared__ float sh_skept;

    if (tid < WCPR) {
        redS[tid] = psum[(size_t)row * WCPR + tid];
        redM[tid] = pmaxv[(size_t)row * WCPR + tid];
    }
    int cnt = gcnt[row];
    int C = min(cnt, CAPG);
    for (int c = tid; c < C; c += NT) {
        s_val[c] = gval[(size_t)row * CAPG + c];
        s_idx[c] = gidx[(size_t)row * CAPG + c];
    }
    __syncthreads();
    if (tid == 0) {
        float S = 0.0f, M = -FLT_MAX;
        for (int i = 0; i < WCPR; ++i) { S += redS[i]; M = fmaxf(M, redM[i]); }  // fixed order: deterministic
        sh_S = S; sh_m = M;
    }
    __syncthreads();
    const float S_K = sh_S;
    const float m_t = sh_m;

    // ---- rare fallback: fixed theta missed — rescan row with adaptive theta ----
    if (C < KMAX) {
        if (tid == 0) s_cnt = 0;
        __syncthreads();
        const float th2t = m_t - FBDELTA;
        const vf4* l4 = (const vf4*)(logits + base);
        for (int j = tid; j < NCHUNK; j += NT) {
            vf4 v = __builtin_nontemporal_load(&l4[j]);
            float t0 = fmaf(v.x, a, b);
            float t1 = fmaf(v.y, a, b);
            float t2 = fmaf(v.z, a, b);
            float t3 = fmaf(v.w, a, b);
            int bi = j * 4;
            if (t0 > th2t) { int p = atomicAdd(&s_cnt, 1); if (p < CAP) { s_val[p] = v.x / T; s_idx[p] = bi;     } }
            if (t1 > th2t) { int p = atomicAdd(&s_cnt, 1); if (p < CAP) { s_val[p] = v.y / T; s_idx[p] = bi + 1; } }
            if (t2 > th2t) { int p = atomicAdd(&s_cnt, 1); if (p < CAP) { s_val[p] = v.z / T; s_idx[p] = bi + 2; } }
            if (t3 > th2t) { int p = atomicAdd(&s_cnt, 1); if (p < CAP) { s_val[p] = v.w / T; s_idx[p] = bi + 3; } }
        }
        __syncthreads();
        C = min(s_cnt, CAP);
    }

    // ---- rank candidates on exact x (stable: value desc, index asc); keep top-KMAX ----
    for (int c = tid; c < C; c += NT) {
        float vc = s_val[c]; int ic = s_idx[c];
        int r = 0;
        #pragma unroll 4
        for (int j = 0; j < C; ++j) {
            float vj = s_val[j];
            if (vj > vc || (vj == vc && s_idx[j] < ic)) r++;
        }
        if (r < KMAX) { so_val[r] = vc; so_idx[r] = ic; }
    }
    __syncthreads();

    // ---- top-p prefix walk + top-k cap; replicate reference addition order ----
    if (tid == 0) {
        int k = topkP[0]; if (k > KMAX) k = KMAX; if (k < 1) k = 1;
        const float topp = toppP[0];
        const int lim = min(C, k);
        float cum = 0.0f;
        float skept = 0.0f;
        int nk = 0;
        for (int j = 0; j < lim; ++j) {
            if (cum > topp) break;
            float e = exp2f(fmaf(so_val[j], LOG2E, b));
            cum += e / S_K;
            skept += e;
            nk++;
        }
        sh_nk = nk;
        sh_skept = skept;
    }
    __syncthreads();
    const int nk = sh_nk;
    const float skept = sh_skept;

    // ---- Gumbel argmax over kept tokens (wave 0 only; first-index tie-break) ----
    if (wid == 0) {
        float bv = -FLT_MAX; int bi = 0x7FFFFFFF; float bx = 0.0f;
        if (lane < nk) {
            int gi = so_idx[lane];
            bx = so_val[lane];
            bv = bx + gumbel[base + gi];
            bi = gi;
        }
        #pragma unroll
        for (int o = 32; o > 0; o >>= 1) {
            float ov = __shfl_down(bv, o, 64);
            int   oi = __shfl_down(bi, o, 64);
            float ox = __shfl_down(bx, o, 64);
            if (ov > bv || (ov == bv && oi < bi)) { bv = ov; bi = oi; bx = ox; }
        }
        if (lane == 0) {
            float eb = exp2f(fmaf(bx, LOG2E, b));
            float confv = eb / skept;
            out_conf[row]  = confv;
            out_x0[row]    = (float)bi;
            out_iconf[row] = confv;
        }
    }
}

// ---------------- Legacy single-kernel path (R5, proven) — used if ws too small ----
#define PROCESS(v, jj)                                                              \
    {                                                                               \
        float t0 = fmaf((v).x, a, b);                                               \
        float t1 = fmaf((v).y, a, b);                                               \
        float t2 = fmaf((v).z, a, b);                                               \
        float t3 = fmaf((v).w, a, b);                                               \
        sA += exp2f(t0);                                                            \
        sB += exp2f(t1);                                                            \
        sA += exp2f(t2);                                                            \
        sB += exp2f(t3);                                                            \
        tmax = fmaxf(tmax, fmaxf(fmaxf(t0, t1), fmaxf(t2, t3)));                    \
        int bi = (jj) * 4;                                                          \
        if (t0 > THT) { int p = atomicAdd(&s_cnt, 1); if (p < CAP) { s_val[p] = (v).x / T; s_idx[p] = bi;     } } \
        if (t1 > THT) { int p = atomicAdd(&s_cnt, 1); if (p < CAP) { s_val[p] = (v).y / T; s_idx[p] = bi + 1; } } \
        if (t2 > THT) { int p = atomicAdd(&s_cnt, 1); if (p < CAP) { s_val[p] = (v).z / T; s_idx[p] = bi + 2; } } \
        if (t3 > THT) { int p = atomicAdd(&s_cnt, 1); if (p < CAP) { s_val[p] = (v).w / T; s_idx[p] = bi + 3; } } \
    }

__global__ __launch_bounds__(NT, 8) void dream_row_legacy(
    const float* __restrict__ logits,
    const float* __restrict__ gumbel,
    const float* __restrict__ tempP,
    const float* __restrict__ toppP,
    const int*   __restrict__ topkP,
    float* __restrict__ out_conf,
    float* __restrict__ out_x0,
    float* __restrict__ out_iconf)
{
    const int row = blockIdx.x;
    const int tid = threadIdx.x;
    const int lane = tid & 63;
    const int wid  = tid >> 6;
    const size_t base = (size_t)row * VOCAB;
    const vf4* l4 = (const vf4*)(logits + base);
    const float T = tempP[0];
    const float a = (1.0f / T) * LOG2E;
    const float b = -(KREF * LOG2E);

    __shared__ float s_val[CAP];
    __shared__ int   s_idx[CAP];
    __shared__ int   s_cnt;
    __shared__ float wsum[NWAVES], wmax[NWAVES];
    __shared__ float sh_S, sh_m;
    __shared__ float so_val[KMAX];
    __shared__ int   so_idx[KMAX];
    __shared__ int   sh_nk;
    __shared__ float sh_skept;

    if (tid == 0) s_cnt = 0;
    __syncthreads();

    float sA = 0.0f, sB = 0.0f;
    float tmax = -FLT_MAX;
    int j0 = tid;
    #pragma unroll 1
    for (int kb = 0; kb < 3; ++kb) {
        vf4 r0 = __builtin_nontemporal_load(&l4[j0 + 0 * NT]);
        vf4 r1 = __builtin_nontemporal_load(&l4[j0 + 1 * NT]);
        vf4 r2 = __builtin_nontemporal_load(&l4[j0 + 2 * NT]);
        vf4 r3 = __builtin_nontemporal_load(&l4[j0 + 3 * NT]);
        vf4 r4 = __builtin_nontemporal_load(&l4[j0 + 4 * NT]);
        vf4 r5 = __builtin_nontemporal_load(&l4[j0 + 5 * NT]);
        vf4 r6 = __builtin_nontemporal_load(&l4[j0 + 6 * NT]);
        vf4 r7 = __builtin_nontemporal_load(&l4[j0 + 7 * NT]);
        PROCESS(r0, j0 + 0 * NT);
        PROCESS(r1, j0 + 1 * NT);
        PROCESS(r2, j0 + 2 * NT);
        PROCESS(r3, j0 + 3 * NT);
        PROCESS(r4, j0 + 4 * NT);
        PROCESS(r5, j0 + 5 * NT);
        PROCESS(r6, j0 + 6 * NT);
        PROCESS(r7, j0 + 7 * NT);
        j0 += 8 * NT;
    }
    {
        vf4 r0 = __builtin_nontemporal_load(&l4[j0 + 0 * NT]);
        vf4 r1 = __builtin_nontemporal_load(&l4[j0 + 1 * NT]);
        vf4 r2 = __builtin_nontemporal_load(&l4[j0 + 2 * NT]);
        vf4 r3 = __builtin_nontemporal_load(&l4[j0 + 3 * NT]);
        vf4 r4 = __builtin_nontemporal_load(&l4[j0 + 4 * NT]);
        vf4 r5 = __builtin_nontemporal_load(&l4[j0 + 5 * NT]);
        vf4 r6 = __builtin_nontemporal_load(&l4[j0 + 6 * NT]);
        PROCESS(r0, j0 + 0 * NT);
        PROCESS(r1, j0 + 1 * NT);
        PROCESS(r2, j0 + 2 * NT);
        PROCESS(r3, j0 + 3 * NT);
        PROCESS(r4, j0 + 4 * NT);
        PROCESS(r5, j0 + 5 * NT);
        PROCESS(r6, j0 + 6 * NT);
        j0 += 7 * NT;
    }
    if (j0 < NCHUNK) {
        vf4 v = __builtin_nontemporal_load(&l4[j0]);
        PROCESS(v, j0);
    }

    float s = sA + sB;
    float mx = tmax;
    #pragma unroll
    for (int o = 32; o > 0; o >>= 1) {
        s  += __shfl_down(s, o, 64);
        mx  = fmaxf(mx, __shfl_down(mx, o, 64));
    }
    if (lane == 0) { wsum[wid] = s; wmax[wid] = mx; }
    __syncthreads();
    if (tid == 0) {
        float St = 0.0f, Mt = -FLT_MAX;
        #pragma unroll
        for (int w = 0; w < NWAVES; ++w) { St += wsum[w]; Mt = fmaxf(Mt, wmax[w]); }
        sh_S = St; sh_m = Mt;
    }
    __syncthreads();
    const float S_K = sh_S;
    const float m_t = sh_m;
    int C = min(s_cnt, CAP);

    if (C < KMAX) {
        if (tid == 0) s_cnt = 0;
        __syncthreads();
        const float th2t = m_t - FBDELTA;
        for (int j = tid; j < NCHUNK; j += NT) {
            vf4 v = __builtin_nontemporal_load(&l4[j]);
            float t0 = fmaf(v.x, a, b);
            float t1 = fmaf(v.y, a, b);
            float t2 = fmaf(v.z, a, b);
            float t3 = fmaf(v.w, a, b);
            int bi = j * 4;
            if (t0 > th2t) { int p = atomicAdd(&s_cnt, 1); if (p < CAP) { s_val[p] = v.x / T; s_idx[p] = bi;     } }
            if (t1 > th2t) { int p = atomicAdd(&s_cnt, 1); if (p < CAP) { s_val[p] = v.y / T; s_idx[p] = bi + 1; } }
            if (t2 > th2t) { int p = atomicAdd(&s_cnt, 1); if (p < CAP) { s_val[p] = v.z / T; s_idx[p] = bi + 2; } }
            if (t3 > th2t) { int p = atomicAdd(&s_cnt, 1); if (p < CAP) { s_val[p] = v.w / T; s_idx[p] = bi + 3; } }
        }
        __syncthreads();
        C = min(s_cnt, CAP);
    }

    for (int c = tid; c < C; c += NT) {
        float vc = s_val[c]; int ic = s_idx[c];
        int r = 0;
        #pragma unroll 4
        for (int j = 0; j < C; ++j) {
            float vj = s_val[j];
            if (vj > vc || (vj == vc && s_idx[j] < ic)) r++;
        }
        if (r < KMAX) { so_val[r] = vc; so_idx[r] = ic; }
    }
    __syncthreads();

    if (tid == 0) {
        int k = topkP[0]; if (k > KMAX) k = KMAX; if (k < 1) k = 1;
        const float topp = toppP[0];
        const int lim = min(C, k);
        float cum = 0.0f;
        float skept = 0.0f;
        int nk = 0;
        for (int j = 0; j < lim; ++j) {
            if (cum > topp) break;
            float e = exp2f(fmaf(so_val[j], LOG2E, b));
            cum += e / S_K;
            skept += e;
            nk++;
        }
        sh_nk = nk;
        sh_skept = skept;
    }
    __syncthreads();
    const int nk = sh_nk;
    const float skept = sh_skept;

    if (wid == 0) {
        float bv = -FLT_MAX; int bi = 0x7FFFFFFF; float bx = 0.0f;
        if (lane < nk) {
            int gi = so_idx[lane];
            bx = so_val[lane];
            bv = bx + gumbel[base + gi];
            bi = gi;
        }
        #pragma unroll
        for (int o = 32; o > 0; o >>= 1) {
            float ov = __shfl_down(bv, o, 64);
            int   oi = __shfl_down(bi, o, 64);
            float ox = __shfl_down(bx, o, 64);
            if (ov > bv || (ov == bv && oi < bi)) { bv = ov; bi = oi; bx = ox; }
        }
        if (lane == 0) {
            float eb = exp2f(fmaf(bx, LOG2E, b));
            float confv = eb / skept;
            out_conf[row]  = confv;
            out_x0[row]    = (float)bi;
            out_iconf[row] = confv;
        }
    }
}

// Global accept step: any(conf > thr) ? per-row high : one-hot at argmax(conf)
__global__ __launch_bounds__(NT) void accept_kernel(
    const float* __restrict__ conf,
    const float* __restrict__ thrP,
    float* __restrict__ acc_out,
    int N)
{
    __shared__ float rv[NT];
    __shared__ int   ri[NT];
    __shared__ int   ra[NT];
    const int tid = threadIdx.x;
    const float thr = thrP[0];

    float bv = -FLT_MAX; int bi = 0x7FFFFFFF; int any = 0;
    for (int i = tid; i < N; i += NT) {
        float v = conf[i];
        if (v > thr) any = 1;
        if (v > bv) { bv = v; bi = i; }
    }
    rv[tid] = bv; ri[tid] = bi; ra[tid] = any;
    __syncthreads();
    #pragma unroll
    for (int s = NT / 2; s > 0; s >>= 1) {
        if (tid < s) {
            float ov = rv[tid + s]; int oi = ri[tid + s];
            if (ov > rv[tid] || (ov == rv[tid] && oi < ri[tid])) {
                rv[tid] = ov; ri[tid] = oi;
            }
            ra[tid] |= ra[tid + s];
        }
        __syncthreads();
    }
    const int anyHigh = ra[0];
    const int amax = ri[0];
    for (int i = tid; i < N; i += NT) {
        float a;
        if (anyHigh) a = (conf[i] > thr) ? 1.0f : 0.0f;
        else         a = (i == amax) ? 1.0f : 0.0f;
        acc_out[i] = a;
    }
}

extern "C" void kernel_launch(void* const* d_in, const int* in_sizes, int n_in,
                              void* d_out, int out_size, void* d_ws, size_t ws_size,
                              hipStream_t stream)
{
    const float* logits = (const float*)d_in[0];
    const float* gumbel = (const float*)d_in[1];
    const float* tempP  = (const float*)d_in[2];
    const float* toppP  = (const float*)d_in[3];
    const int*   topkP  = (const int*)d_in[4];
    const float* thrP   = (const float*)d_in[5];
    float* out = (float*)d_out;
    const int N = in_sizes[0] / VOCAB;

    // workspace layout (256B-aligned sections)
    auto al = [](size_t x) { return (x + 255) & ~(size_t)255; };
    size_t gcnt_o = 0;
    size_t psum_o = al(gcnt_o + (size_t)N * 4);
    size_t pmax_o = al(psum_o + (size_t)N * WCPR * 4);
    size_t gval_o = al(pmax_o + (size_t)N * WCPR * 4);
    size_t gidx_o = al(gval_o + (size_t)N * CAPG * 4);
    size_t need   = gidx_o + (size_t)N * CAPG * 4;

    if (ws_size >= need) {
        char* ws = (char*)d_ws;
        int*   gcnt  = (int*)(ws + gcnt_o);
        float* psum  = (float*)(ws + psum_o);
        float* pmaxv = (float*)(ws + pmax_o);
        float* gval  = (float*)(ws + gval_o);
        int*   gidx  = (int*)(ws + gidx_o);

        hipMemsetAsync(gcnt, 0, (size_t)N * 4, stream);
        sweep_kernel<<<2048, NT, 0, stream>>>(
            logits, tempP, gcnt, psum, pmaxv, gval, gidx, N);
        finalize_kernel<<<N, NT, 0, stream>>>(
            logits, gumbel, tempP, toppP, topkP,
            gcnt, psum, pmaxv, gval, gidx,
            out /*confidence*/, out + N /*x0*/, out + 2 * N /*initial_confidence*/);
    } else {
        dream_row_legacy<<<N, NT, 0, stream>>>(
            logits, gumbel, tempP, toppP, topkP,
            out, out + N, out + 2 * N);
    }

    accept_kernel<<<1, NT, 0, stream>>>(
        out, thrP, out + 3 * N /*accepted*/, N);
}

// Round 8
// 522.863 us; speedup vs baseline: 1.3542x; 1.3542x over previous
//
#include <hip/hip_runtime.h>
#include <math.h>
#include <float.h>

#define VOCAB    32000
#define NT       256
#define NWAVES   (NT / 64)
#define CAP      1024    // candidate buffer; E[count]=228 at THETA0, 52-sigma headroom
#define KMAX     64      // >= top_k (50)
#define KREF     24.0f   // fixed exp reference point (x_max ~ 24; exp(x-KREF) in [2e-22, ~2])
#define THETA0   14.0f   // collection threshold in x units; 50th-largest ~16.1 +- 0.25
#define LOG2E    1.4426950408889634f
// collection threshold in t-units: t = (x - KREF)*log2e
#define THT      ((THETA0 - KREF) * LOG2E)
#define FBDELTA  (12.0f * LOG2E)
#define NCHUNK   (VOCAB / 4)   // 8000 float4 per row = 31*256 + 64

typedef float vf4 __attribute__((ext_vector_type(4)));

// R8 probe: R5 structure (per-row block, 8-deep register-staged batches,
// launch_bounds(256,8)) with PLAIN loads -- single-variable test of the nt
// modifier in the batched regime. nt bypasses L1/L2 allocation; suspicion is it
// forfeits L2 memory-side 128B read combining and pins reads at ~1.7 TB/s.
// Everything else (summation order, ranking, top-p walk, Gumbel argmax) is
// byte-identical to the R5-verified kernel -> absmax must remain 0.

#define PROCESS(v, jj)                                                              \
    {                                                                               \
        float t0 = fmaf((v).x, a, b);                                               \
        float t1 = fmaf((v).y, a, b);                                               \
        float t2 = fmaf((v).z, a, b);                                               \
        float t3 = fmaf((v).w, a, b);                                               \
        sA += exp2f(t0);                                                            \
        sB += exp2f(t1);                                                            \
        sA += exp2f(t2);                                                            \
        sB += exp2f(t3);                                                            \
        tmax = fmaxf(tmax, fmaxf(fmaxf(t0, t1), fmaxf(t2, t3)));                    \
        int bi = (jj) * 4;                                                          \
        if (t0 > THT) { int p = atomicAdd(&s_cnt, 1); if (p < CAP) { s_val[p] = (v).x / T; s_idx[p] = bi;     } } \
        if (t1 > THT) { int p = atomicAdd(&s_cnt, 1); if (p < CAP) { s_val[p] = (v).y / T; s_idx[p] = bi + 1; } } \
        if (t2 > THT) { int p = atomicAdd(&s_cnt, 1); if (p < CAP) { s_val[p] = (v).z / T; s_idx[p] = bi + 2; } } \
        if (t3 > THT) { int p = atomicAdd(&s_cnt, 1); if (p < CAP) { s_val[p] = (v).w / T; s_idx[p] = bi + 3; } } \
    }

__global__ __launch_bounds__(NT, 8) void dream_row_kernel(
    const float* __restrict__ logits,
    const float* __restrict__ gumbel,
    const float* __restrict__ tempP,
    const float* __restrict__ toppP,
    const int*   __restrict__ topkP,
    float* __restrict__ out_conf,
    float* __restrict__ out_x0,
    float* __restrict__ out_iconf)
{
    const int row = blockIdx.x;
    const int tid = threadIdx.x;
    const int lane = tid & 63;
    const int wid  = tid >> 6;
    const size_t base = (size_t)row * VOCAB;
    const vf4* l4 = (const vf4*)(logits + base);
    const float T = tempP[0];
    const float a = (1.0f / T) * LOG2E;        // t = v*a + b  (monotone in v)
    const float b = -(KREF * LOG2E);

    __shared__ float s_val[CAP];   // exact x = v/T for candidates
    __shared__ int   s_idx[CAP];
    __shared__ int   s_cnt;
    __shared__ float wsum[NWAVES], wmax[NWAVES];
    __shared__ float sh_S, sh_m;
    __shared__ float so_val[KMAX];
    __shared__ int   so_idx[KMAX];
    __shared__ int   sh_nk;
    __shared__ float sh_skept;

    if (tid == 0) s_cnt = 0;
    __syncthreads();

    // ---- streaming pass: 8-deep register-staged PLAIN loads, then consume ----
    float sA = 0.0f, sB = 0.0f;
    float tmax = -FLT_MAX;
    int j0 = tid;

    #pragma unroll 1
    for (int kb = 0; kb < 3; ++kb) {
        vf4 r0 = l4[j0 + 0 * NT];
        vf4 r1 = l4[j0 + 1 * NT];
        vf4 r2 = l4[j0 + 2 * NT];
        vf4 r3 = l4[j0 + 3 * NT];
        vf4 r4 = l4[j0 + 4 * NT];
        vf4 r5 = l4[j0 + 5 * NT];
        vf4 r6 = l4[j0 + 6 * NT];
        vf4 r7 = l4[j0 + 7 * NT];
        PROCESS(r0, j0 + 0 * NT);
        PROCESS(r1, j0 + 1 * NT);
        PROCESS(r2, j0 + 2 * NT);
        PROCESS(r3, j0 + 3 * NT);
        PROCESS(r4, j0 + 4 * NT);
        PROCESS(r5, j0 + 5 * NT);
        PROCESS(r6, j0 + 6 * NT);
        PROCESS(r7, j0 + 7 * NT);
        j0 += 8 * NT;
    }
    // batch of 7 (k = 24..30)
    {
        vf4 r0 = l4[j0 + 0 * NT];
        vf4 r1 = l4[j0 + 1 * NT];
        vf4 r2 = l4[j0 + 2 * NT];
        vf4 r3 = l4[j0 + 3 * NT];
        vf4 r4 = l4[j0 + 4 * NT];
        vf4 r5 = l4[j0 + 5 * NT];
        vf4 r6 = l4[j0 + 6 * NT];
        PROCESS(r0, j0 + 0 * NT);
        PROCESS(r1, j0 + 1 * NT);
        PROCESS(r2, j0 + 2 * NT);
        PROCESS(r3, j0 + 3 * NT);
        PROCESS(r4, j0 + 4 * NT);
        PROCESS(r5, j0 + 5 * NT);
        PROCESS(r6, j0 + 6 * NT);
        j0 += 7 * NT;
    }
    // tail: k = 31, only tid < 64 in range (8000 - 7936)
    if (j0 < NCHUNK) {
        vf4 v = l4[j0];
        PROCESS(v, j0);
    }

    // ---- wave-shuffle reduce, then tiny cross-wave combine ----
    float s = sA + sB;
    float mx = tmax;
    #pragma unroll
    for (int o = 32; o > 0; o >>= 1) {
        s  += __shfl_down(s, o, 64);
        mx  = fmaxf(mx, __shfl_down(mx, o, 64));
    }
    if (lane == 0) { wsum[wid] = s; wmax[wid] = mx; }
    __syncthreads();
    if (tid == 0) {
        float St = 0.0f, Mt = -FLT_MAX;
        #pragma unroll
        for (int w = 0; w < NWAVES; ++w) { St += wsum[w]; Mt = fmaxf(Mt, wmax[w]); }
        sh_S = St; sh_m = Mt;
    }
    __syncthreads();
    const float S_K = sh_S;          // = sum exp2(t) = sum exp(x - KREF)
    const float m_t = sh_m;          // row max in t-units (fallback guard only)
    int C = min(s_cnt, CAP);

    // ---- rare fallback: fixed theta missed — recollect with adaptive theta ----
    if (C < KMAX) {
        if (tid == 0) s_cnt = 0;
        __syncthreads();
        const float th2t = m_t - FBDELTA;   // == (x_max - 12) in t-units
        for (int j = tid; j < NCHUNK; j += NT) {
            vf4 v = l4[j];
            float t0 = fmaf(v.x, a, b);
            float t1 = fmaf(v.y, a, b);
            float t2 = fmaf(v.z, a, b);
            float t3 = fmaf(v.w, a, b);
            int bi = j * 4;
            if (t0 > th2t) { int p = atomicAdd(&s_cnt, 1); if (p < CAP) { s_val[p] = v.x / T; s_idx[p] = bi;     } }
            if (t1 > th2t) { int p = atomicAdd(&s_cnt, 1); if (p < CAP) { s_val[p] = v.y / T; s_idx[p] = bi + 1; } }
            if (t2 > th2t) { int p = atomicAdd(&s_cnt, 1); if (p < CAP) { s_val[p] = v.z / T; s_idx[p] = bi + 2; } }
            if (t3 > th2t) { int p = atomicAdd(&s_cnt, 1); if (p < CAP) { s_val[p] = v.w / T; s_idx[p] = bi + 3; } }
        }
        __syncthreads();
        C = min(s_cnt, CAP);
    }

    // ---- rank candidates on exact x (stable: value desc, index asc); keep top-KMAX ----
    for (int c = tid; c < C; c += NT) {
        float vc = s_val[c]; int ic = s_idx[c];
        int r = 0;
        #pragma unroll 4
        for (int j = 0; j < C; ++j) {
            float vj = s_val[j];
            if (vj > vc || (vj == vc && s_idx[j] < ic)) r++;
        }
        if (r < KMAX) { so_val[r] = vc; so_idx[r] = ic; }
    }
    __syncthreads();

    // ---- top-p prefix walk + top-k cap; replicate reference addition order ----
    if (tid == 0) {
        int k = topkP[0]; if (k > KMAX) k = KMAX; if (k < 1) k = 1;
        const float topp = toppP[0];
        const int lim = min(C, k);
        float cum = 0.0f;     // prob mass of ranks before j (full softmax)
        float skept = 0.0f;   // K-referenced masked softmax denominator
        int nk = 0;
        for (int j = 0; j < lim; ++j) {
            if (cum > topp) break;          // rank j removed iff cum_{j-1} > top_p
            float e = exp2f(fmaf(so_val[j], LOG2E, b));   // = exp(x_j - KREF)
            cum += e / S_K;
            skept += e;
            nk++;
        }
        sh_nk = nk;
        sh_skept = skept;
    }
    __syncthreads();
    const int nk = sh_nk;
    const float skept = sh_skept;

    // ---- Gumbel argmax over kept tokens (wave 0 only; first-index tie-break) ----
    if (wid == 0) {
        float bv = -FLT_MAX; int bi = 0x7FFFFFFF; float bx = 0.0f;
        if (lane < nk) {
            int gi = so_idx[lane];
            bx = so_val[lane];                 // exact x
            bv = bx + gumbel[base + gi];
            bi = gi;
        }
        #pragma unroll
        for (int o = 32; o > 0; o >>= 1) {
            float ov = __shfl_down(bv, o, 64);
            int   oi = __shfl_down(bi, o, 64);
            float ox = __shfl_down(bx, o, 64);
            if (ov > bv || (ov == bv && oi < bi)) { bv = ov; bi = oi; bx = ox; }
        }
        if (lane == 0) {
            float eb = exp2f(fmaf(bx, LOG2E, b));    // = exp(x0 - KREF)
            float confv = eb / skept;                // probs[x0] of masked softmax
            out_conf[row]  = confv;
            out_x0[row]    = (float)bi;
            out_iconf[row] = confv;
        }
    }
}

// Global accept step: any(conf > thr) ? per-row high : one-hot at argmax(conf)
__global__ __launch_bounds__(NT) void accept_kernel(
    const float* __restrict__ conf,
    const float* __restrict__ thrP,
    float* __restrict__ acc_out,
    int N)
{
    __shared__ float rv[NT];
    __shared__ int   ri[NT];
    __shared__ int   ra[NT];
    const int tid = threadIdx.x;
    const float thr = thrP[0];

    float bv = -FLT_MAX; int bi = 0x7FFFFFFF; int any = 0;
    for (int i = tid; i < N; i += NT) {
        float v = conf[i];
        if (v > thr) any = 1;
        if (v > bv) { bv = v; bi = i; }   // ascending i -> first occurrence on ties
    }
    rv[tid] = bv; ri[tid] = bi; ra[tid] = any;
    __syncthreads();
    #pragma unroll
    for (int s = NT / 2; s > 0; s >>= 1) {
        if (tid < s) {
            float ov = rv[tid + s]; int oi = ri[tid + s];
            if (ov > rv[tid] || (ov == rv[tid] && oi < ri[tid])) {
                rv[tid] = ov; ri[tid] = oi;
            }
            ra[tid] |= ra[tid + s];
        }
        __syncthreads();
    }
    const int anyHigh = ra[0];
    const int amax = ri[0];
    for (int i = tid; i < N; i += NT) {
        float a;
        if (anyHigh) a = (conf[i] > thr) ? 1.0f : 0.0f;
        else         a = (i == amax) ? 1.0f : 0.0f;
        acc_out[i] = a;
    }
}

extern "C" void kernel_launch(void* const* d_in, const int* in_sizes, int n_in,
                              void* d_out, int out_size, void* d_ws, size_t ws_size,
                              hipStream_t stream)
{
    const float* logits = (const float*)d_in[0];
    const float* gumbel = (const float*)d_in[1];
    const float* tempP  = (const float*)d_in[2];
    const float* toppP  = (const float*)d_in[3];
    const int*   topkP  = (const int*)d_in[4];
    const float* thrP   = (const float*)d_in[5];
    float* out = (float*)d_out;
    const int N = in_sizes[0] / VOCAB;

    dream_row_kernel<<<N, NT, 0, stream>>>(
        logits, gumbel, tempP, toppP, topkP,
        out /*confidence*/, out + N /*x0*/, out + 2 * N /*initial_confidence*/);

    accept_kernel<<<1, NT, 0, stream>>>(
        out, thrP, out + 3 * N /*accepted*/, N);
}